// Round 9
// baseline (78.380 us; speedup 1.0000x reference)
//
#include <hip/hip_runtime.h>
#include <math.h>

#define HH 128
#define BB 2
#define FF 1024
#define CC 16
#define PIF 3.14159265358979323846f

typedef float f2 __attribute__((ext_vector_type(2)));

// ---------------------------------------------------------------------------
// Kernel 1: per-face setup (once, 2048 threads total).
// f32 record (16 floats, 64B):
//   [0..8]  A0 B0 C0 A1 B1 C1 A2 B2 C2   (l_i = A*py + B*px + C, 1/area folded)
//   [9..11] ZA ZB ZC                     (zt = clamp(ZA*py+ZB*px+ZC, 0, 1))
//   [12]    sg   [13] eps (f32 sign-uncertainty band)   [14..15] pad
// f64 record (10 doubles): exact A..C. Used only when min|l_f32| < eps; the
// f64 signs reproduce the exact decisions (R3..R7: absmax 0.008-0.016 vs
// threshold 0.565 -- no boundary-flip lottery).
// ---------------------------------------------------------------------------
__global__ __launch_bounds__(256) void fof_setup(const float* __restrict__ v,
                                                 float* __restrict__ recf,
                                                 double* __restrict__ recd,
                                                 int* __restrict__ bbox) {
    int idx = blockIdx.x * 256 + threadIdx.x;
    if (idx >= BB * FF) return;
    const float* vp = v + (size_t)idx * 9;

    double X0 = fma((double)vp[0],  64.0, 63.5);
    double Y0 = fma((double)vp[1], -64.0, 63.5);
    double Z0 = (double)vp[2];
    double X1 = fma((double)vp[3],  64.0, 63.5);
    double Y1 = fma((double)vp[4], -64.0, 63.5);
    double Z1 = (double)vp[5];
    double X2 = fma((double)vp[6],  64.0, 63.5);
    double Y2 = fma((double)vp[7], -64.0, 63.5);
    double Z2 = (double)vp[8];

    double d0x = X2 - X1, d0y = Y2 - Y1;
    double d1x = X0 - X2, d1y = Y0 - Y2;
    double d2x = X1 - X0, d2y = Y1 - Y0;
    double area = d1x * d2y - d1y * d2x;
    double inv  = (area != 0.0) ? 1.0 / area : 0.0;
    double sg   = (area > 0.0) ? 1.0 : ((area < 0.0) ? -1.0 : 0.0);

    double A0 = d0x * inv, B0 = -d0y * inv, C0 = (d0y * X1 - d0x * Y1) * inv;
    double A1 = d1x * inv, B1 = -d1y * inv, C1 = (d1y * X2 - d1x * Y2) * inv;
    double A2 = d2x * inv, B2 = -d2y * inv, C2 = (d2y * X0 - d2x * Y0) * inv;

    double ZA = (A0 * Z0 + A1 * Z1 + A2 * Z2) * 0.5;
    double ZB = (B0 * Z0 + B1 * Z1 + B2 * Z2) * 0.5;
    double ZC = (C0 * Z0 + C1 * Z1 + C2 * Z2 + 1.0) * 0.5;

    // f32 sign-uncertainty band (f64->f32 conversion + 2-fma eval rounding)
    double M0 = (fabs(A0) + fabs(B0)) * 135.0 + fabs(C0);
    double M1 = (fabs(A1) + fabs(B1)) * 135.0 + fabs(C1);
    double M2 = (fabs(A2) + fabs(B2)) * 135.0 + fabs(C2);
    float eps = (float)(1e-6 * fmax(M0, fmax(M1, M2)));

    float* rf = recf + (size_t)idx * 16;
    rf[0] = (float)A0; rf[1] = (float)B0; rf[2] = (float)C0;
    rf[3] = (float)A1; rf[4] = (float)B1; rf[5] = (float)C1;
    rf[6] = (float)A2; rf[7] = (float)B2; rf[8] = (float)C2;
    rf[9] = (float)ZA; rf[10] = (float)ZB; rf[11] = (float)ZC;
    rf[12] = (float)sg; rf[13] = eps; rf[14] = 0.f; rf[15] = 0.f;

    double* rd = recd + (size_t)idx * 10;
    rd[0] = A0; rd[1] = B0; rd[2] = C0;
    rd[3] = A1; rd[4] = B1; rd[5] = C1;
    rd[6] = A2; rd[7] = B2; rd[8] = C2; rd[9] = 0.0;

    float x0 = (float)X0, y0 = (float)Y0;
    float x1 = (float)X1, y1 = (float)Y1;
    float x2 = (float)X2, y2 = (float)Y2;
    float xmn = fminf(x0, fminf(x1, x2)) - 0.5f;
    float xmx = fmaxf(x0, fmaxf(x1, x2)) + 0.5f;
    float ymn = fminf(y0, fminf(y1, y2)) - 0.5f;
    float ymx = fmaxf(y0, fmaxf(y1, y2)) + 0.5f;
    int txmin = (int)ceilf((xmn - 7.f) * 0.125f);
    int txmax = (int)floorf(xmx * 0.125f);
    int tymin = (int)ceilf((ymn - 7.f) * 0.125f);
    int tymax = (int)floorf(ymx * 0.125f);
    txmin = max(0, min(15, txmin)); txmax = max(0, min(15, txmax));
    tymin = max(0, min(15, tymin)); tymax = max(0, min(15, tymax));
    bbox[idx] = (sg == 0.0) ? (1 | (0 << 8) | (1 << 16) | (0 << 24))
                            : (txmin | (txmax << 8) | (tymin << 16) | (tymax << 24));
}

// ---------------------------------------------------------------------------
// Kernel 2: main. 1024 blocks x 512 threads (8 waves x 64 faces = half the
// faces per block; 2 blocks per (b,tile) accumulate via atomicAdd).
// Block->(tile,b,half) mapping is dispatch-order-robust:
//   u2 = bit-scatter of u=blk&255, kb = blk>>8, tile = u2 ^ (kb*0x55).
//   depth-first fill: co-resident blocks are quadrant mirrors -> per-CU
//   load flattens (radial profile p(x)+p(x+8) ~ const);
//   round-robin fill: XOR set {00,55,AA,FF} stratifies both axes.
// Survivor loop is software-pipelined: next record's scalars (wave-uniform
// s_load) are issued before the current body computes.
// BUGFIX vs R8: next-survivor index used ctzll(m|1), which is ALWAYS 0
// (bit 0 forced set) -> processed face 0 repeatedly and dropped real
// survivors. Now msafe = m | (m==0): identity for m!=0, ctz(1)=0 only in
// the (unused, hn=false) empty case.
// ---------------------------------------------------------------------------
__global__ __launch_bounds__(512) void fof_main(const float* __restrict__ recf,
                                                const double* __restrict__ recd,
                                                const int* __restrict__ bbox,
                                                float* __restrict__ out) {
    __shared__ float S1[4][64][17];
    __shared__ float S2[2][64][17];
    __shared__ float S3[64][17];

    int i  = blockIdx.x;              // 0..1023
    int u  = i & 255;
    int kb = i >> 8;                  // 0..3
    int u2 = ((u & 1) << 3) | ((u & 2) << 6) | ((u >> 2) & 7) | (((u >> 5) & 7) << 4);
    int tile = u2 ^ (kb * 0x55);
    int b    = kb & 1;
    int half = kb >> 1;
    int ty   = tile >> 4;
    int tx   = tile & 15;
    int wv   = __builtin_amdgcn_readfirstlane((int)(threadIdx.x >> 6));  // 0..7
    int lane = threadIdx.x & 63;

    float px = (float)(tx * 8 + (lane & 7));
    float py = (float)(ty * 8 + (lane >> 3));

    float acc0 = 0.f, acc15 = 0.f;
    f2 accP[7];
#pragma unroll
    for (int j = 0; j < 7; ++j) { accP[j].x = 0.f; accP[j].y = 0.f; }

    int gfb = b * FF + half * 512 + wv * 64;   // this wave's 64-face chunk

    int pk = bbox[gfb + lane];
    int txmin = pk & 255, txmax = (pk >> 8) & 255;
    int tymin = (pk >> 16) & 255, tymax = (pk >> 24) & 255;
    bool pass = !((tx < txmin) | (tx > txmax) | (ty < tymin) | (ty > tymax));
    unsigned long long m = __ballot(pass);

    if (m) {
        int j = __builtin_amdgcn_readfirstlane(__builtin_ctzll(m));
        m &= m - 1;
        const float* r = recf + (size_t)(gfb + j) * 16;
        float cA0 = r[0], cB0 = r[1], cC0 = r[2];
        float cA1 = r[3], cB1 = r[4], cC1 = r[5];
        float cA2 = r[6], cB2 = r[7], cC2 = r[8];
        float cZA = r[9], cZB = r[10], cZC = r[11];
        float cSg = r[12], cEps = r[13];

        for (;;) {
            // ---- prefetch next survivor's record ----
            bool hn = (m != 0);
            unsigned long long msafe = m | (unsigned long long)(m == 0);
            int jn = __builtin_amdgcn_readfirstlane(__builtin_ctzll(msafe));
            m &= m - 1;                                  // 0 stays 0
            const float* rn = recf + (size_t)(gfb + jn) * 16;
            float nA0 = rn[0], nB0 = rn[1], nC0 = rn[2];
            float nA1 = rn[3], nB1 = rn[4], nC1 = rn[5];
            float nA2 = rn[6], nB2 = rn[7], nC2 = rn[8];
            float nZA = rn[9], nZB = rn[10], nZC = rn[11];
            float nSg = rn[12], nEps = rn[13];

            // ---- body on current record ----
            float l0 = fmaf(cA0, py, fmaf(cB0, px, cC0));
            float l1 = fmaf(cA1, py, fmaf(cB1, px, cC1));
            float l2 = fmaf(cA2, py, fmaf(cB2, px, cC2));
            float lmin = fminf(fminf(l0, l1), l2);
            float amin = fminf(fminf(__builtin_fabsf(l0), __builtin_fabsf(l1)),
                               __builtin_fabsf(l2));
            bool inside = lmin >= 0.f;
            if (__builtin_expect(__any(amin < cEps), 0)) {   // rare exact path
                const double* rd = recd + (size_t)(gfb + j) * 10;
                double pyd = (double)py, pxd = (double)px;
                double L0 = fma(rd[0], pyd, fma(rd[1], pxd, rd[2]));
                double L1 = fma(rd[3], pyd, fma(rd[4], pxd, rd[5]));
                double L2 = fma(rd[6], pyd, fma(rd[7], pxd, rd[8]));
                inside = (L0 >= 0.0) & (L1 >= 0.0) & (L2 >= 0.0);
            }
            float w = inside ? cSg : 0.f;

            if (__any(w != 0.f)) {
                float zt = fmaf(cZA, py, fmaf(cZB, px, cZC));
                zt = fminf(fmaxf(zt, 0.f), 1.f);
                // HW trig in revolutions: sin(pi zt)=vsin(zt/2),
                // sin(2pi zt)=vsin(zt), cos(2pi zt)=vcos(zt); zt in [0,1].
                float hz = 0.5f * zt;
                float s1, s2, c2;
                asm("v_sin_f32 %0, %1" : "=v"(s1) : "v"(hz));
                asm("v_sin_f32 %0, %1" : "=v"(s2) : "v"(zt));
                asm("v_cos_f32 %0, %1" : "=v"(c2) : "v"(zt));
                float twoc2 = c2 + c2;

                acc0 = fmaf(w, 1.f - zt, acc0);
                f2 w2;  w2.x = w;      w2.y = w;
                f2 t2;  t2.x = twoc2;  t2.y = twoc2;
                f2 um1; um1.x = -s1;   um1.y = 0.f;   // (s_{-1}, s_0)
                f2 u0;  u0.x = s1;     u0.y = s2;     // (s_1, s_2)
                accP[0] += w2 * u0;
                f2 u1 = t2 * u0 - um1;  accP[1] += w2 * u1;   // (s_3, s_4)
                f2 uu2 = t2 * u1 - u0;  accP[2] += w2 * uu2;  // (s_5, s_6)
                f2 u3 = t2 * uu2 - u1;  accP[3] += w2 * u3;   // (s_7, s_8)
                f2 u4 = t2 * u3 - uu2;  accP[4] += w2 * u4;   // (s_9, s_10)
                f2 u5 = t2 * u4 - u3;   accP[5] += w2 * u5;   // (s_11,s_12)
                f2 u6 = t2 * u5 - u4;   accP[6] += w2 * u6;   // (s_13,s_14)
                float s15 = fmaf(twoc2, u6.x, -u5.x);
                acc15 = fmaf(w, s15, acc15);
            }

            if (!hn) break;
            // ---- shift pipeline ----
            j = jn;
            cA0 = nA0; cB0 = nB0; cC0 = nC0;
            cA1 = nA1; cB1 = nB1; cC1 = nC1;
            cA2 = nA2; cB2 = nB2; cC2 = nC2;
            cZA = nZA; cZB = nZB; cZC = nZC;
            cSg = nSg; cEps = nEps;
        }
    }

    float accv[16];
    accv[0] = acc0;
#pragma unroll
    for (int j = 0; j < 7; ++j) { accv[2 * j + 1] = accP[j].x; accv[2 * j + 2] = accP[j].y; }
    accv[15] = acc15;

    // 8 -> 4 -> 2 -> 1 tree (disjoint stage buffers)
    if (wv >= 4) {
#pragma unroll
        for (int k = 0; k < CC; ++k) S1[wv - 4][lane][k] = accv[k];
    }
    __syncthreads();
    if (wv < 4) {
#pragma unroll
        for (int k = 0; k < CC; ++k) accv[k] += S1[wv][lane][k];
    }
    if (wv == 2 || wv == 3) {
#pragma unroll
        for (int k = 0; k < CC; ++k) S2[wv - 2][lane][k] = accv[k];
    }
    __syncthreads();
    if (wv < 2) {
#pragma unroll
        for (int k = 0; k < CC; ++k) accv[k] += S2[wv][lane][k];
    }
    if (wv == 1) {
#pragma unroll
        for (int k = 0; k < CC; ++k) S3[lane][k] = accv[k];
    }
    __syncthreads();
    if (wv == 0) {
        int xo = tx * 8 + (lane & 7);
        int yo = ty * 8 + (lane >> 3);
#pragma unroll
        for (int k = 0; k < CC; ++k) {
            float val = accv[k] + S3[lane][k];
            float scale = (k == 0) ? 1.f : (-2.f / (PIF * (float)k));
            atomicAdd(&out[(((b * CC + k) * HH) + yo) * HH + xo], val * scale);
        }
    }
}

extern "C" void kernel_launch(void* const* d_in, const int* in_sizes, int n_in,
                              void* d_out, int out_size, void* d_ws, size_t ws_size,
                              hipStream_t stream) {
    const float* v = (const float*)d_in[0];
    float* out = (float*)d_out;

    // ws: recf 2048*16*4 = 131072 B | recd 2048*10*8 = 163840 B | bbox 8192 B
    float*  recf = (float*)d_ws;
    double* recd = (double*)((char*)d_ws + 131072);
    int*    bbox = (int*)((char*)d_ws + 131072 + 163840);

    hipMemsetAsync(d_out, 0, (size_t)out_size * sizeof(float), stream);
    fof_setup<<<(BB * FF + 255) / 256, 256, 0, stream>>>(v, recf, recd, bbox);
    fof_main<<<BB * 2 * 256, 512, 0, stream>>>(recf, recd, bbox, out);
}